// Round 9
// baseline (325.521 us; speedup 1.0000x reference)
//
#include <hip/hip_runtime.h>
#include <hip/hip_bf16.h>
#include <math.h>

#define NB 4
#define LIN 40960
#define NC 512
#define T0 8192
#define T1 2048
#define T2 1024
#define T3 512
#define TN 256
#define DM 2048
#define EPSF 1e-5f
#define TEMPF 1e-5f

typedef __attribute__((ext_vector_type(8))) short bf16x8;
typedef __attribute__((ext_vector_type(4))) float f32x4;

__device__ __forceinline__ int refl(int t, int T) {
  if (t < 0) t = -t;
  if (t >= T) t = 2 * T - 2 - t;
  return t;
}

__device__ __forceinline__ void gld16(void* lds, const void* g) {
  __builtin_amdgcn_global_load_lds((const __attribute__((address_space(1))) unsigned int*)g,
                                   (__attribute__((address_space(3))) unsigned int*)lds, 16, 0, 0);
}

__device__ __forceinline__ void blk_sum2_512(float& a, float& b, float* scratch) {
#pragma unroll
  for (int off = 32; off > 0; off >>= 1) {
    a += __shfl_down(a, off, 64);
    b += __shfl_down(b, off, 64);
  }
  int lane = threadIdx.x & 63, wid = threadIdx.x >> 6;
  __syncthreads();
  if (lane == 0) { scratch[wid] = a; scratch[8 + wid] = b; }
  __syncthreads();
  float sa = 0.f, sb = 0.f;
#pragma unroll
  for (int i = 0; i < 8; i++) { sa += scratch[i]; sb += scratch[8 + i]; }
  a = sa; b = sb;
}

// load 8 bf16 (16B) -> 8 floats, accumulate
__device__ __forceinline__ void add_bf8(const __hip_bfloat16* p, float* v) {
  union { uint4 u; __hip_bfloat16 h[8]; } pk;
  pk.u = *(const uint4*)p;
#pragma unroll
  for (int j = 0; j < 8; j++) v[j] += __bfloat162float(pk.h[j]);
}

// ---------------- weight prep (single kernel) ----------------
template <int KT>
__device__ __forceinline__ void prep_conv_body(const float* __restrict__ w, __hip_bfloat16* __restrict__ wt,
                                               int co, float* l) {
  const float* wb = w + (size_t)co * 512 * KT;
  for (int i = threadIdx.x; i < 512 * KT; i += 256) l[i] = wb[i];
  __syncthreads();
  __hip_bfloat16* wo = wt + (size_t)co * 512 * KT;
  for (int i = threadIdx.x; i < 512 * KT; i += 256) {
    int kk = i >> 9, ci = i & 511;
    wo[i] = __float2bfloat16(l[ci * KT + kk]);
  }
}

template <int KD, int ND>
__device__ __forceinline__ void prep_mlp_body(const float* __restrict__ w, __hip_bfloat16* __restrict__ wt,
                                              int bidx, float* sbuf) {
  float(*tile)[33] = (float(*)[33])sbuf;
  int bx = bidx % (ND / 32);
  int by = bidx / (ND / 32);
  int tx = threadIdx.x & 31, ty = threadIdx.x >> 5;
#pragma unroll
  for (int i = 0; i < 32; i += 8)
    tile[ty + i][tx] = w[(size_t)(by * 32 + ty + i) * ND + bx * 32 + tx];
  __syncthreads();
#pragma unroll
  for (int i = 0; i < 32; i += 8)
    wt[(size_t)(bx * 32 + ty + i) * KD + by * 32 + tx] = __float2bfloat16(tile[tx][ty + i]);
}

// 512+512+512+1024+4096 = 6656 blocks
__global__ __launch_bounds__(256) void k_prep(const float* c1w, const float* c2w, const float* c3w,
                                              const float* mw1, const float* mw2,
                                              __hip_bfloat16* wt1, __hip_bfloat16* wt2,
                                              __hip_bfloat16* wt3, __hip_bfloat16* wm1t,
                                              __hip_bfloat16* wm2t) {
  __shared__ float sb[4096];
  int b = blockIdx.x;
  if (b < 512) prep_conv_body<8>(c1w, wt1, b, sb);
  else if (b < 1024) prep_conv_body<4>(c2w, wt2, b - 512, sb);
  else if (b < 1536) prep_conv_body<4>(c3w, wt3, b - 1024, sb);
  else if (b < 2560) prep_mlp_body<512, 2048>(mw1, wm1t, b - 1536, sb);
  else prep_mlp_body<2048, 2048>(mw2, wm2t, b - 2560, sb);
}

// ---------------- conv0 + ChannelNorm + ReLU -> bf16 ----------------
__global__ __launch_bounds__(512) void k_conv0(const float* __restrict__ x, const float* __restrict__ w,
                                               const float* __restrict__ bias, const float* __restrict__ gw,
                                               const float* __restrict__ gb, __hip_bfloat16* __restrict__ out) {
  __shared__ float xv[48];
  __shared__ float tb[512 * 9];
  __shared__ float stats[16];
  int b = blockIdx.x / (T0 / 8);
  int t0 = (blockIdx.x % (T0 / 8)) * 8;
  int tid = threadIdx.x;
  if (tid < 45) xv[tid] = x[(size_t)b * LIN + refl(t0 * 5 - 3 + tid, LIN)];
  __syncthreads();
  float wk[10];
#pragma unroll
  for (int k = 0; k < 10; k++) wk[k] = w[tid * 10 + k];
  float bs = bias[tid];
  float acc[8];
#pragma unroll
  for (int tt = 0; tt < 8; tt++) {
    float a = bs;
#pragma unroll
    for (int k = 0; k < 10; k++) a += xv[tt * 5 + k] * wk[k];
    acc[tt] = a;
    tb[tid * 9 + tt] = a;
  }
  __syncthreads();
  int wave = tid >> 6, lane = tid & 63;
  float s = 0.f, q = 0.f;
#pragma unroll
  for (int j = 0; j < 8; j++) {
    float v = tb[(lane * 8 + j) * 9 + wave];
    s += v; q += v * v;
  }
#pragma unroll
  for (int off = 32; off > 0; off >>= 1) {
    s += __shfl_xor(s, off, 64);
    q += __shfl_xor(q, off, 64);
  }
  if (lane == 0) {
    float mean = s * (1.f / NC);
    float var = fmaxf((q - s * s * (1.f / NC)) * (1.f / (NC - 1)), 0.f);
    stats[wave] = mean;
    stats[8 + wave] = rsqrtf(var + EPSF);
  }
  __syncthreads();
  float gwv = gw[tid], gbv = gb[tid];
#pragma unroll
  for (int tt = 0; tt < 8; tt++) {
    float y = (acc[tt] - stats[tt]) * stats[8 + tt] * gwv + gbv;
    out[((size_t)(b * T0 + t0 + tt)) * NC + tid] = __float2bfloat16(fmaxf(y, 0.f));
  }
}

// ---------------- MFMA GEMM v2: 128x128 tile, BK=32, dbuf, split-K, bf16 partials ----
// __launch_bounds__(256,4): cap regs at 128/wave (64 AGPR + <=64 VGPR) -> 4 blocks/CU.
template <int MODE, int TIN_, int TOUT_, int SS, int PP, int KK, int NN, int SPLITK, int MM>
__global__ __launch_bounds__(256, 4) void k_gemm2(const __hip_bfloat16* __restrict__ A,
                                                  const __hip_bfloat16* __restrict__ Bt,
                                                  __hip_bfloat16* __restrict__ Cp) {
  __shared__ __align__(16) __hip_bfloat16 sA[2][128 * 32];
  __shared__ __align__(16) __hip_bfloat16 sB[2][128 * 32];
  const int tid = threadIdx.x;
  const int lane = tid & 63;
  const int wave = tid >> 6;
  const int wm = wave >> 1, wn = wave & 1;
  constexpr int nt = NN / 128;
  constexpr int PS = (MM / 1024) * nt;
  constexpr int KBT = KK / 32;
  const int blk = blockIdx.x;
  const int xs = blk & 7, sl = blk >> 3;
  const int sk = sl / PS, rem = sl % PS;
  const int row0 = ((rem / nt) * 8 + xs) * 128;
  const int col0 = (rem % nt) * 128;
  const int kb0 = (sk * KBT) / SPLITK, kb1 = ((sk + 1) * KBT) / SPLITK;
  const int cq = lane >> 4, cl = lane & 15;

  auto stage = [&](int kb, int buf) {
#pragma unroll
    for (int rr = 0; rr < 2; rr++) {
      int c = rr * 256 + tid;
      int m = c >> 2, kc = c & 3;
      int kcs = kc ^ (m & 3);
      size_t ga;
      if (MODE == 0) {
        ga = (size_t)(row0 + m) * KK + kb * 32 + kcs * 8;
      } else {
        int r = row0 + m;
        int bb = r / TOUT_;
        int t = r - bb * TOUT_;
        int k = (kb * 32) >> 9;
        int ci = ((kb * 32) & 511) + kcs * 8;
        int gt = refl(t * SS - PP + k, TIN_);
        ga = (((size_t)(bb * TIN_ + gt)) << 9) + ci;
      }
      gld16((char*)&sA[buf][0] + c * 16, (const char*)(A + ga));
    }
#pragma unroll
    for (int rr = 0; rr < 2; rr++) {
      int c = rr * 256 + tid;
      int n = c >> 2, kc = c & 3;
      int kcs = kc ^ (n & 3);
      gld16((char*)&sB[buf][0] + c * 16, (const char*)(Bt + (size_t)(col0 + n) * KK + kb * 32 + kcs * 8));
    }
  };

  f32x4 acc[4][4];
  const f32x4 zz = {0.f, 0.f, 0.f, 0.f};
#pragma unroll
  for (int mi = 0; mi < 4; mi++)
#pragma unroll
    for (int ni = 0; ni < 4; ni++) acc[mi][ni] = zz;

  stage(kb0, 0);
  const int p = cq ^ (cl & 3);
  for (int kb = kb0; kb < kb1; kb++) {
    int cur = (kb - kb0) & 1;
    __syncthreads();
    if (kb + 1 < kb1) stage(kb + 1, cur ^ 1);
    const short* bA = (const short*)&sA[cur][0];
    const short* bB = (const short*)&sB[cur][0];
    bf16x8 af[4], bfr[4];
#pragma unroll
    for (int mi = 0; mi < 4; mi++)
      af[mi] = *(const bf16x8*)(bA + (wm * 64 + mi * 16 + cl) * 32 + p * 8);
#pragma unroll
    for (int ni = 0; ni < 4; ni++)
      bfr[ni] = *(const bf16x8*)(bB + (wn * 64 + ni * 16 + cl) * 32 + p * 8);
#pragma unroll
    for (int mi = 0; mi < 4; mi++)
#pragma unroll
      for (int ni = 0; ni < 4; ni++)
        acc[mi][ni] = __builtin_amdgcn_mfma_f32_16x16x32_bf16(af[mi], bfr[ni], acc[mi][ni], 0, 0, 0);
  }

  // C/D: col=lane&15, row=(lane>>4)*4+reg; bf16 partial out
#pragma unroll
  for (int mi = 0; mi < 4; mi++)
#pragma unroll
    for (int ni = 0; ni < 4; ni++)
#pragma unroll
      for (int r2 = 0; r2 < 4; r2++) {
        int row = row0 + wm * 64 + mi * 16 + cq * 4 + r2;
        int col = col0 + wn * 64 + ni * 16 + cl;
        Cp[(size_t)sk * MM * NN + (size_t)row * NN + col] = __float2bfloat16(acc[mi][ni][r2]);
      }
}

// ---------------- MFMA GEMM v1: 64x128 tile (conv3, mlp1) ----------
// EPI 0: bf16 partial to Cout + sk*MM*NN. EPI 1: +bias, exact GELU -> bf16 Cout.
template <int MODE, int TIN_, int TOUT_, int SS, int PP, int KK, int NN, int EPI, int SPLITK, int MM>
__global__ __launch_bounds__(256, 4) void k_gemm(const __hip_bfloat16* __restrict__ A,
                                                 const __hip_bfloat16* __restrict__ Bt,
                                                 const float* __restrict__ bias,
                                                 __hip_bfloat16* __restrict__ Cout) {
  __shared__ __align__(16) __hip_bfloat16 sA[2][64 * 32];
  __shared__ __align__(16) __hip_bfloat16 sB[2][128 * 32];
  const int tid = threadIdx.x;
  const int lane = tid & 63;
  const int wave = tid >> 6;
  const int wm = wave >> 1, wn = wave & 1;
  constexpr int nt = NN / 128;
  constexpr int PS = (MM / 512) * nt;
  constexpr int KBT = KK / 32;
  const int blk = blockIdx.x;
  const int xs = blk & 7, sl = blk >> 3;
  const int sk = sl / PS, rem = sl % PS;
  const int row0 = ((rem / nt) * 8 + xs) * 64;
  const int col0 = (rem % nt) * 128;
  const int kb0 = (sk * KBT) / SPLITK, kb1 = ((sk + 1) * KBT) / SPLITK;
  const int cq = lane >> 4, cl = lane & 15;

  auto stage = [&](int kb, int buf) {
    {
      int m = tid >> 2, kc = tid & 3;
      int kcs = kc ^ (m & 3);
      size_t ga;
      if (MODE == 0) {
        ga = (size_t)(row0 + m) * KK + kb * 32 + kcs * 8;
      } else {
        int r = row0 + m;
        int bb = r / TOUT_;
        int t = r - bb * TOUT_;
        int k = (kb * 32) >> 9;
        int ci = ((kb * 32) & 511) + kcs * 8;
        int gt = refl(t * SS - PP + k, TIN_);
        ga = (((size_t)(bb * TIN_ + gt)) << 9) + ci;
      }
      gld16((char*)&sA[buf][0] + tid * 16, (const char*)(A + ga));
    }
#pragma unroll
    for (int rr = 0; rr < 2; rr++) {
      int c = rr * 256 + tid;
      int n = c >> 2, kc = c & 3;
      int kcs = kc ^ (n & 3);
      gld16((char*)&sB[buf][0] + c * 16, (const char*)(Bt + (size_t)(col0 + n) * KK + kb * 32 + kcs * 8));
    }
  };

  f32x4 acc[2][4];
  const f32x4 zz = {0.f, 0.f, 0.f, 0.f};
#pragma unroll
  for (int mi = 0; mi < 2; mi++)
#pragma unroll
    for (int ni = 0; ni < 4; ni++) acc[mi][ni] = zz;

  stage(kb0, 0);
  const int p = cq ^ (cl & 3);
  for (int kb = kb0; kb < kb1; kb++) {
    int cur = (kb - kb0) & 1;
    __syncthreads();
    if (kb + 1 < kb1) stage(kb + 1, cur ^ 1);
    const short* bA = (const short*)&sA[cur][0];
    const short* bB = (const short*)&sB[cur][0];
    bf16x8 af[2], bfr[4];
#pragma unroll
    for (int mi = 0; mi < 2; mi++)
      af[mi] = *(const bf16x8*)(bA + (wm * 32 + mi * 16 + cl) * 32 + p * 8);
#pragma unroll
    for (int ni = 0; ni < 4; ni++)
      bfr[ni] = *(const bf16x8*)(bB + (wn * 64 + ni * 16 + cl) * 32 + p * 8);
#pragma unroll
    for (int mi = 0; mi < 2; mi++)
#pragma unroll
      for (int ni = 0; ni < 4; ni++)
        acc[mi][ni] = __builtin_amdgcn_mfma_f32_16x16x32_bf16(af[mi], bfr[ni], acc[mi][ni], 0, 0, 0);
  }

#pragma unroll
  for (int mi = 0; mi < 2; mi++)
#pragma unroll
    for (int ni = 0; ni < 4; ni++)
#pragma unroll
      for (int r2 = 0; r2 < 4; r2++) {
        int row = row0 + wm * 32 + mi * 16 + cq * 4 + r2;
        int col = col0 + wn * 64 + ni * 16 + cl;
        float v = acc[mi][ni][r2];
        if (EPI == 1) {
          v += bias[col];
          v = 0.5f * v * (1.f + erff(v * 0.70710678118654752f));
          Cout[(size_t)row * NN + col] = __float2bfloat16(v);
        } else {
          Cout[(size_t)sk * MM * NN + (size_t)row * NN + col] = __float2bfloat16(v);
        }
      }
}

// ---------------- ChannelNorm (+conv bias, sum NS bf16 split-K partials) + ReLU -> bf16
template <int NS>
__global__ __launch_bounds__(512) void k_cnorm(const __hip_bfloat16* __restrict__ g,
                                               const float* __restrict__ cb,
                                               const float* __restrict__ gw, const float* __restrict__ gb,
                                               __hip_bfloat16* __restrict__ out, size_t stride) {
  int wave = threadIdx.x >> 6, lane = threadIdx.x & 63;
  size_t row = (size_t)blockIdx.x * 8 + wave;
  float v[8];
  {
    float4 c0 = *(const float4*)(cb + lane * 8), c1 = *(const float4*)(cb + lane * 8 + 4);
    v[0] = c0.x; v[1] = c0.y; v[2] = c0.z; v[3] = c0.w;
    v[4] = c1.x; v[5] = c1.y; v[6] = c1.z; v[7] = c1.w;
  }
#pragma unroll
  for (int s = 0; s < NS; s++) add_bf8(g + s * stride + row * NC + lane * 8, v);
  float s = 0.f, q = 0.f;
#pragma unroll
  for (int j = 0; j < 8; j++) { s += v[j]; q += v[j] * v[j]; }
#pragma unroll
  for (int off = 32; off > 0; off >>= 1) {
    s += __shfl_xor(s, off, 64);
    q += __shfl_xor(q, off, 64);
  }
  float mean = s * (1.f / NC);
  float var = fmaxf((q - s * s * (1.f / NC)) * (1.f / (NC - 1)), 0.f);
  float rstd = rsqrtf(var + EPSF);
  float4 w0 = *(const float4*)(gw + lane * 8), w1 = *(const float4*)(gw + lane * 8 + 4);
  float4 b0 = *(const float4*)(gb + lane * 8), b1 = *(const float4*)(gb + lane * 8 + 4);
  float gwv[8] = {w0.x, w0.y, w0.z, w0.w, w1.x, w1.y, w1.z, w1.w};
  float gbv[8] = {b0.x, b0.y, b0.z, b0.w, b1.x, b1.y, b1.z, b1.w};
  union { __hip_bfloat16 h[8]; uint4 u; } pk;
#pragma unroll
  for (int j = 0; j < 8; j++)
    pk.h[j] = __float2bfloat16(fmaxf((v[j] - mean) * rstd * gwv[j] + gbv[j], 0.f));
  *(uint4*)(out + row * NC + lane * 8) = pk.u;
}

// ---------------- fused head: sum NS bf16 partials + bias + GELU, dot w3, sigmoid ----
template <int NS>
__global__ __launch_bounds__(256) void k_head(const __hip_bfloat16* __restrict__ g,
                                              const float* __restrict__ b2,
                                              const float* __restrict__ w3, const float* __restrict__ b3,
                                              float* __restrict__ imp) {
  __shared__ float red[4];
  int row = blockIdx.x, tid = threadIdx.x;
  int c = tid * 8;
  float v[8];
  {
    float4 x0 = *(const float4*)(b2 + c), x1 = *(const float4*)(b2 + c + 4);
    v[0] = x0.x; v[1] = x0.y; v[2] = x0.z; v[3] = x0.w;
    v[4] = x1.x; v[5] = x1.y; v[6] = x1.z; v[7] = x1.w;
  }
#pragma unroll
  for (int s = 0; s < NS; s++) add_bf8(g + (size_t)s * (2048 * DM) + (size_t)row * DM + c, v);
  float a = 0.f;
  float4 w0 = *(const float4*)(w3 + c), w1 = *(const float4*)(w3 + c + 4);
  float wv[8] = {w0.x, w0.y, w0.z, w0.w, w1.x, w1.y, w1.z, w1.w};
#pragma unroll
  for (int j = 0; j < 8; j++) {
    float z = 0.5f * v[j] * (1.f + erff(v[j] * 0.70710678118654752f));
    a += z * wv[j];
  }
#pragma unroll
  for (int off = 32; off > 0; off >>= 1) a += __shfl_down(a, off, 64);
  int lane = tid & 63, wid = tid >> 6;
  if (lane == 0) red[wid] = a;
  __syncthreads();
  if (tid == 0) {
    float s = red[0] + red[1] + red[2] + red[3] + b3[0];
    imp[row] = 1.f / (1.f + expf(-s)) + TEMPF;
  }
}

__device__ __forceinline__ float dfun(float cv, int n) {
  float d = fmaxf(cv - (float)n, 0.f);
  if (n < TN - 1) d = fminf(d, 1.f);
  return d;
}

// ---------------- fused cumsum + pool + final ChannelNorm + ReLU, write [B][C][TN] ----
__global__ __launch_bounds__(512) void k_poolfinal(const __hip_bfloat16* __restrict__ f,
                                                   const float* __restrict__ imp,
                                                   const float* __restrict__ gw, const float* __restrict__ gb,
                                                   float* __restrict__ out) {
  __shared__ float wt[T3];
  __shared__ float wsum[8];
  __shared__ float red[16];
  int b = blockIdx.x / TN, n = blockIdx.x % TN;
  int tid = threadIdx.x, wave = tid >> 6, lane = tid & 63;
  float own = imp[b * T3 + tid];
  float s = own;
#pragma unroll
  for (int off = 1; off < 64; off <<= 1) {
    float t = __shfl_up(s, off, 64);
    if (lane >= off) s += t;
  }
  if (lane == 63) wsum[wave] = s;
  __syncthreads();
  float prefix = 0.f, total = 0.f;
#pragma unroll
  for (int w = 0; w < 8; w++) {
    float ws_ = wsum[w];
    total += ws_;
    if (w < wave) prefix += ws_;
  }
  float scale = (float)TN / total;
  float incl = (prefix + s) * scale;
  float excl = (prefix + s - own) * scale;
  wt[tid] = dfun(incl, n) - dfun(excl, n);
  __syncthreads();
  float acc = 0.f;
  for (int t = 0; t < T3; t++) {
    float w = wt[t];
    if (w != 0.f) acc += w * __bfloat162float(f[((size_t)b * T3 + t) * NC + tid]);
  }
  float sv = acc, q = acc * acc;
  blk_sum2_512(sv, q, red);
  float mean = sv * (1.f / NC);
  float var = fmaxf((q - sv * sv * (1.f / NC)) * (1.f / (NC - 1)), 0.f);
  float y = (acc - mean) * rsqrtf(var + EPSF) * gw[tid] + gb[tid];
  out[((size_t)b * NC + tid) * TN + n] = fmaxf(y, 0.f);
}

extern "C" void kernel_launch(void* const* d_in, const int* in_sizes, int n_in,
                              void* d_out, int out_size, void* d_ws, size_t ws_size,
                              hipStream_t stream) {
  const float* x   = (const float*)d_in[0];
  const float* c0w = (const float*)d_in[1];  const float* c0b = (const float*)d_in[2];
  const float* c1w = (const float*)d_in[3];  const float* c1b = (const float*)d_in[4];
  const float* c2w = (const float*)d_in[5];  const float* c2b = (const float*)d_in[6];
  const float* c3w = (const float*)d_in[7];  const float* c3b = (const float*)d_in[8];
  const float* mw1 = (const float*)d_in[9];  const float* mb1 = (const float*)d_in[10];
  const float* mw2 = (const float*)d_in[11]; const float* mb2 = (const float*)d_in[12];
  const float* mw3 = (const float*)d_in[13]; const float* mb3 = (const float*)d_in[14];
  const float* n0w = (const float*)d_in[15]; const float* n0b = (const float*)d_in[16];
  const float* n1w = (const float*)d_in[17]; const float* n1b = (const float*)d_in[18];
  const float* n2w = (const float*)d_in[19]; const float* n2b = (const float*)d_in[20];
  const float* n3w = (const float*)d_in[21]; const float* n3b = (const float*)d_in[22];
  const float* n4w = (const float*)d_in[23]; const float* n4b = (const float*)d_in[24];

  char* base = (char*)d_ws;
  // Workspace map (MiB). Peak 82 MiB.
  __hip_bfloat16* h0b  = (__hip_bfloat16*)(base);                     // [0,32): conv0 out; dead after conv1-gemm
  __hip_bfloat16* h1b  = (__hip_bfloat16*)(base);                     // reuse [0,8)
  __hip_bfloat16* h2b  = (__hip_bfloat16*)(base + (8u << 20));        // reuse [8,12)
  __hip_bfloat16* h3b  = (__hip_bfloat16*)(base + (12u << 20));       // reuse [12,14)
  __hip_bfloat16* z1b  = (__hip_bfloat16*)(base + (14u << 20));       // reuse [14,22)
  float*          imp  = (float*)(base + (22u << 20));                // reuse [22,+8K)
  __hip_bfloat16* g    = (__hip_bfloat16*)(base + (32u << 20));       // [32,64): bf16 split-K partials
  __hip_bfloat16* wm1t = (__hip_bfloat16*)(base + (64u << 20));       // [64,66)
  __hip_bfloat16* wt2  = (__hip_bfloat16*)(base + (66u << 20));       // [66,68)
  __hip_bfloat16* wt3  = (__hip_bfloat16*)(base + (68u << 20));       // [68,70)
  __hip_bfloat16* wt1  = (__hip_bfloat16*)(base + (70u << 20));       // [70,74)
  __hip_bfloat16* wm2t = (__hip_bfloat16*)(base + (74u << 20));       // [74,82)
  float* outp = (float*)d_out;

  k_prep<<<6656, 256, 0, stream>>>(c1w, c2w, c3w, mw1, mw2, wt1, wt2, wt3, wm1t, wm2t);
  k_conv0<<<NB * (T0 / 8), 512, 0, stream>>>(x, c0w, c0b, n0w, n0b, h0b);

  // conv1: M=8192, K=4096, N=512, SK4 -> 1024 blocks (4/CU @ 128-reg cap)
  k_gemm2<1, 8192, 2048, 4, 2, 4096, 512, 4, 8192><<<1024, 256, 0, stream>>>(h0b, wt1, g);
  k_cnorm<4><<<8192 / 8, 512, 0, stream>>>(g, c1b, n1w, n1b, h1b, (size_t)8192 * 512);
  // conv2: M=4096, K=2048, SK8 -> 1024 blocks
  k_gemm2<1, 2048, 1024, 2, 1, 2048, 512, 8, 4096><<<1024, 256, 0, stream>>>(h1b, wt2, g);
  k_cnorm<8><<<4096 / 8, 512, 0, stream>>>(g, c2b, n2w, n2b, h2b, (size_t)4096 * 512);
  // conv3: M=2048, K=2048, 64x128 tiles, SK8 -> 1024 blocks
  k_gemm<1, 1024, 512, 2, 1, 2048, 512, 0, 8, 2048><<<1024, 256, 0, stream>>>(h2b, wt3, nullptr, g);
  k_cnorm<8><<<2048 / 8, 512, 0, stream>>>(g, c3b, n3w, n3b, h3b, (size_t)2048 * 512);

  // mlp1: M=2048, K=512, N=2048, EPI=GELU -> 512 blocks
  k_gemm<0, 0, 1, 0, 0, 512, 2048, 1, 1, 2048><<<512, 256, 0, stream>>>(h3b, wm1t, mb1, z1b);
  // mlp2: M=2048, K=2048, N=2048, SK4 -> 1024 blocks; head consumes bf16 partials
  k_gemm2<0, 0, 1, 0, 0, 2048, 2048, 4, 2048><<<1024, 256, 0, stream>>>(z1b, wm2t, g);

  k_head<4><<<NB * T3, 256, 0, stream>>>(g, mb2, mw3, mb3, imp);
  k_poolfinal<<<NB * TN, 512, 0, stream>>>(h3b, imp, n4w, n4b, outp);
}

// Round 10
// 324.945 us; speedup vs baseline: 1.0018x; 1.0018x over previous
//
#include <hip/hip_runtime.h>
#include <hip/hip_bf16.h>
#include <math.h>

#define NB 4
#define LIN 40960
#define NC 512
#define T0 8192
#define T1 2048
#define T2 1024
#define T3 512
#define TN 256
#define DM 2048
#define EPSF 1e-5f
#define TEMPF 1e-5f

typedef __attribute__((ext_vector_type(8))) short bf16x8;
typedef __attribute__((ext_vector_type(4))) float f32x4;

__device__ __forceinline__ int refl(int t, int T) {
  if (t < 0) t = -t;
  if (t >= T) t = 2 * T - 2 - t;
  return t;
}

__device__ __forceinline__ void gld16(void* lds, const void* g) {
  __builtin_amdgcn_global_load_lds((const __attribute__((address_space(1))) unsigned int*)g,
                                   (__attribute__((address_space(3))) unsigned int*)lds, 16, 0, 0);
}

__device__ __forceinline__ void blk_sum2_512(float& a, float& b, float* scratch) {
#pragma unroll
  for (int off = 32; off > 0; off >>= 1) {
    a += __shfl_down(a, off, 64);
    b += __shfl_down(b, off, 64);
  }
  int lane = threadIdx.x & 63, wid = threadIdx.x >> 6;
  __syncthreads();
  if (lane == 0) { scratch[wid] = a; scratch[8 + wid] = b; }
  __syncthreads();
  float sa = 0.f, sb = 0.f;
#pragma unroll
  for (int i = 0; i < 8; i++) { sa += scratch[i]; sb += scratch[8 + i]; }
  a = sa; b = sb;
}

// load 8 bf16 (16B) -> 8 floats, accumulate
__device__ __forceinline__ void add_bf8(const __hip_bfloat16* p, float* v) {
  union { uint4 u; __hip_bfloat16 h[8]; } pk;
  pk.u = *(const uint4*)p;
#pragma unroll
  for (int j = 0; j < 8; j++) v[j] += __bfloat162float(pk.h[j]);
}

// ---------------- weight prep (single kernel) ----------------
template <int KT>
__device__ __forceinline__ void prep_conv_body(const float* __restrict__ w, __hip_bfloat16* __restrict__ wt,
                                               int co, float* l) {
  const float* wb = w + (size_t)co * 512 * KT;
  for (int i = threadIdx.x; i < 512 * KT; i += 256) l[i] = wb[i];
  __syncthreads();
  __hip_bfloat16* wo = wt + (size_t)co * 512 * KT;
  for (int i = threadIdx.x; i < 512 * KT; i += 256) {
    int kk = i >> 9, ci = i & 511;
    wo[i] = __float2bfloat16(l[ci * KT + kk]);
  }
}

template <int KD, int ND>
__device__ __forceinline__ void prep_mlp_body(const float* __restrict__ w, __hip_bfloat16* __restrict__ wt,
                                              int bidx, float* sbuf) {
  float(*tile)[33] = (float(*)[33])sbuf;
  int bx = bidx % (ND / 32);
  int by = bidx / (ND / 32);
  int tx = threadIdx.x & 31, ty = threadIdx.x >> 5;
#pragma unroll
  for (int i = 0; i < 32; i += 8)
    tile[ty + i][tx] = w[(size_t)(by * 32 + ty + i) * ND + bx * 32 + tx];
  __syncthreads();
#pragma unroll
  for (int i = 0; i < 32; i += 8)
    wt[(size_t)(bx * 32 + ty + i) * KD + by * 32 + tx] = __float2bfloat16(tile[tx][ty + i]);
}

// 512+512+512+1024+4096 = 6656 blocks
__global__ __launch_bounds__(256) void k_prep(const float* c1w, const float* c2w, const float* c3w,
                                              const float* mw1, const float* mw2,
                                              __hip_bfloat16* wt1, __hip_bfloat16* wt2,
                                              __hip_bfloat16* wt3, __hip_bfloat16* wm1t,
                                              __hip_bfloat16* wm2t) {
  __shared__ float sb[4096];
  int b = blockIdx.x;
  if (b < 512) prep_conv_body<8>(c1w, wt1, b, sb);
  else if (b < 1024) prep_conv_body<4>(c2w, wt2, b - 512, sb);
  else if (b < 1536) prep_conv_body<4>(c3w, wt3, b - 1024, sb);
  else if (b < 2560) prep_mlp_body<512, 2048>(mw1, wm1t, b - 1536, sb);
  else prep_mlp_body<2048, 2048>(mw2, wm2t, b - 2560, sb);
}

// ---------------- conv0 + ChannelNorm + ReLU -> bf16 ----------------
__global__ __launch_bounds__(512) void k_conv0(const float* __restrict__ x, const float* __restrict__ w,
                                               const float* __restrict__ bias, const float* __restrict__ gw,
                                               const float* __restrict__ gb, __hip_bfloat16* __restrict__ out) {
  __shared__ float xv[48];
  __shared__ float tb[512 * 9];
  __shared__ float stats[16];
  int b = blockIdx.x / (T0 / 8);
  int t0 = (blockIdx.x % (T0 / 8)) * 8;
  int tid = threadIdx.x;
  if (tid < 45) xv[tid] = x[(size_t)b * LIN + refl(t0 * 5 - 3 + tid, LIN)];
  __syncthreads();
  float wk[10];
#pragma unroll
  for (int k = 0; k < 10; k++) wk[k] = w[tid * 10 + k];
  float bs = bias[tid];
  float acc[8];
#pragma unroll
  for (int tt = 0; tt < 8; tt++) {
    float a = bs;
#pragma unroll
    for (int k = 0; k < 10; k++) a += xv[tt * 5 + k] * wk[k];
    acc[tt] = a;
    tb[tid * 9 + tt] = a;
  }
  __syncthreads();
  int wave = tid >> 6, lane = tid & 63;
  float s = 0.f, q = 0.f;
#pragma unroll
  for (int j = 0; j < 8; j++) {
    float v = tb[(lane * 8 + j) * 9 + wave];
    s += v; q += v * v;
  }
#pragma unroll
  for (int off = 32; off > 0; off >>= 1) {
    s += __shfl_xor(s, off, 64);
    q += __shfl_xor(q, off, 64);
  }
  if (lane == 0) {
    float mean = s * (1.f / NC);
    float var = fmaxf((q - s * s * (1.f / NC)) * (1.f / (NC - 1)), 0.f);
    stats[wave] = mean;
    stats[8 + wave] = rsqrtf(var + EPSF);
  }
  __syncthreads();
  float gwv = gw[tid], gbv = gb[tid];
#pragma unroll
  for (int tt = 0; tt < 8; tt++) {
    float y = (acc[tt] - stats[tt]) * stats[8 + tt] * gwv + gbv;
    out[((size_t)(b * T0 + t0 + tt)) * NC + tid] = __float2bfloat16(fmaxf(y, 0.f));
  }
}

// ---------------- MFMA GEMM v2: 256x128 block tile, wave=128x64, BK=32, dbuf, SK ----
// LDS bytes/FLOP cut 33% vs 64x64 waves (192B/lane per 8192 FLOP/lane).
// acc[8][4]=128 AGPR + ~64 VGPR -> 2 blocks/CU; grids must be 512.
template <int MODE, int TIN_, int TOUT_, int SS, int PP, int KK, int NN, int SPLITK, int MM>
__global__ __launch_bounds__(256, 2) void k_gemm2(const __hip_bfloat16* __restrict__ A,
                                                  const __hip_bfloat16* __restrict__ Bt,
                                                  __hip_bfloat16* __restrict__ Cp) {
  __shared__ __align__(16) __hip_bfloat16 sA[2][256 * 32];
  __shared__ __align__(16) __hip_bfloat16 sB[2][128 * 32];
  const int tid = threadIdx.x;
  const int lane = tid & 63;
  const int wave = tid >> 6;
  const int wm = wave >> 1, wn = wave & 1;
  constexpr int nt = NN / 128;
  constexpr int PS = (MM / 2048) * nt;  // row-groups(of 8 x 256-row tiles) x col-tiles
  constexpr int KBT = KK / 32;
  const int blk = blockIdx.x;
  const int xs = blk & 7, sl = blk >> 3;
  const int sk = sl / PS, rem = sl % PS;
  const int row0 = ((rem / nt) * 8 + xs) * 256;
  const int col0 = (rem % nt) * 128;
  const int kb0 = (sk * KBT) / SPLITK, kb1 = ((sk + 1) * KBT) / SPLITK;
  const int cq = lane >> 4, cl = lane & 15;

  auto stage = [&](int kb, int buf) {
#pragma unroll
    for (int rr = 0; rr < 4; rr++) {  // A: 256 rows x 4 chunks = 1024 / 256 thr
      int c = rr * 256 + tid;
      int m = c >> 2, kc = c & 3;
      int kcs = kc ^ (m & 3);
      size_t ga;
      if (MODE == 0) {
        ga = (size_t)(row0 + m) * KK + kb * 32 + kcs * 8;
      } else {
        int r = row0 + m;
        int bb = r / TOUT_;
        int t = r - bb * TOUT_;
        int k = (kb * 32) >> 9;
        int ci = ((kb * 32) & 511) + kcs * 8;
        int gt = refl(t * SS - PP + k, TIN_);
        ga = (((size_t)(bb * TIN_ + gt)) << 9) + ci;
      }
      gld16((char*)&sA[buf][0] + c * 16, (const char*)(A + ga));
    }
#pragma unroll
    for (int rr = 0; rr < 2; rr++) {  // B: 128 rows x 4 chunks = 512 / 256 thr
      int c = rr * 256 + tid;
      int n = c >> 2, kc = c & 3;
      int kcs = kc ^ (n & 3);
      gld16((char*)&sB[buf][0] + c * 16, (const char*)(Bt + (size_t)(col0 + n) * KK + kb * 32 + kcs * 8));
    }
  };

  f32x4 acc[8][4];
  const f32x4 zz = {0.f, 0.f, 0.f, 0.f};
#pragma unroll
  for (int mi = 0; mi < 8; mi++)
#pragma unroll
    for (int ni = 0; ni < 4; ni++) acc[mi][ni] = zz;

  stage(kb0, 0);
  const int p = cq ^ (cl & 3);
  for (int kb = kb0; kb < kb1; kb++) {
    int cur = (kb - kb0) & 1;
    __syncthreads();
    if (kb + 1 < kb1) stage(kb + 1, cur ^ 1);
    const short* bA = (const short*)&sA[cur][0];
    const short* bB = (const short*)&sB[cur][0];
    bf16x8 af[8], bfr[4];
#pragma unroll
    for (int mi = 0; mi < 8; mi++)
      af[mi] = *(const bf16x8*)(bA + (wm * 128 + mi * 16 + cl) * 32 + p * 8);
#pragma unroll
    for (int ni = 0; ni < 4; ni++)
      bfr[ni] = *(const bf16x8*)(bB + (wn * 64 + ni * 16 + cl) * 32 + p * 8);
#pragma unroll
    for (int mi = 0; mi < 8; mi++)
#pragma unroll
      for (int ni = 0; ni < 4; ni++)
        acc[mi][ni] = __builtin_amdgcn_mfma_f32_16x16x32_bf16(af[mi], bfr[ni], acc[mi][ni], 0, 0, 0);
  }

  // C/D: col=lane&15, row=(lane>>4)*4+reg; bf16 partial out
#pragma unroll
  for (int mi = 0; mi < 8; mi++)
#pragma unroll
    for (int ni = 0; ni < 4; ni++)
#pragma unroll
      for (int r2 = 0; r2 < 4; r2++) {
        int row = row0 + wm * 128 + mi * 16 + cq * 4 + r2;
        int col = col0 + wn * 64 + ni * 16 + cl;
        Cp[(size_t)sk * MM * NN + (size_t)row * NN + col] = __float2bfloat16(acc[mi][ni][r2]);
      }
}

// ---------------- MFMA GEMM v1: 64x128 tile (conv3, mlp1) ----------
// EPI 0: bf16 partial to Cout + sk*MM*NN. EPI 1: +bias, exact GELU -> bf16 Cout.
template <int MODE, int TIN_, int TOUT_, int SS, int PP, int KK, int NN, int EPI, int SPLITK, int MM>
__global__ __launch_bounds__(256, 4) void k_gemm(const __hip_bfloat16* __restrict__ A,
                                                 const __hip_bfloat16* __restrict__ Bt,
                                                 const float* __restrict__ bias,
                                                 __hip_bfloat16* __restrict__ Cout) {
  __shared__ __align__(16) __hip_bfloat16 sA[2][64 * 32];
  __shared__ __align__(16) __hip_bfloat16 sB[2][128 * 32];
  const int tid = threadIdx.x;
  const int lane = tid & 63;
  const int wave = tid >> 6;
  const int wm = wave >> 1, wn = wave & 1;
  constexpr int nt = NN / 128;
  constexpr int PS = (MM / 512) * nt;
  constexpr int KBT = KK / 32;
  const int blk = blockIdx.x;
  const int xs = blk & 7, sl = blk >> 3;
  const int sk = sl / PS, rem = sl % PS;
  const int row0 = ((rem / nt) * 8 + xs) * 64;
  const int col0 = (rem % nt) * 128;
  const int kb0 = (sk * KBT) / SPLITK, kb1 = ((sk + 1) * KBT) / SPLITK;
  const int cq = lane >> 4, cl = lane & 15;

  auto stage = [&](int kb, int buf) {
    {
      int m = tid >> 2, kc = tid & 3;
      int kcs = kc ^ (m & 3);
      size_t ga;
      if (MODE == 0) {
        ga = (size_t)(row0 + m) * KK + kb * 32 + kcs * 8;
      } else {
        int r = row0 + m;
        int bb = r / TOUT_;
        int t = r - bb * TOUT_;
        int k = (kb * 32) >> 9;
        int ci = ((kb * 32) & 511) + kcs * 8;
        int gt = refl(t * SS - PP + k, TIN_);
        ga = (((size_t)(bb * TIN_ + gt)) << 9) + ci;
      }
      gld16((char*)&sA[buf][0] + tid * 16, (const char*)(A + ga));
    }
#pragma unroll
    for (int rr = 0; rr < 2; rr++) {
      int c = rr * 256 + tid;
      int n = c >> 2, kc = c & 3;
      int kcs = kc ^ (n & 3);
      gld16((char*)&sB[buf][0] + c * 16, (const char*)(Bt + (size_t)(col0 + n) * KK + kb * 32 + kcs * 8));
    }
  };

  f32x4 acc[2][4];
  const f32x4 zz = {0.f, 0.f, 0.f, 0.f};
#pragma unroll
  for (int mi = 0; mi < 2; mi++)
#pragma unroll
    for (int ni = 0; ni < 4; ni++) acc[mi][ni] = zz;

  stage(kb0, 0);
  const int p = cq ^ (cl & 3);
  for (int kb = kb0; kb < kb1; kb++) {
    int cur = (kb - kb0) & 1;
    __syncthreads();
    if (kb + 1 < kb1) stage(kb + 1, cur ^ 1);
    const short* bA = (const short*)&sA[cur][0];
    const short* bB = (const short*)&sB[cur][0];
    bf16x8 af[2], bfr[4];
#pragma unroll
    for (int mi = 0; mi < 2; mi++)
      af[mi] = *(const bf16x8*)(bA + (wm * 32 + mi * 16 + cl) * 32 + p * 8);
#pragma unroll
    for (int ni = 0; ni < 4; ni++)
      bfr[ni] = *(const bf16x8*)(bB + (wn * 64 + ni * 16 + cl) * 32 + p * 8);
#pragma unroll
    for (int mi = 0; mi < 2; mi++)
#pragma unroll
      for (int ni = 0; ni < 4; ni++)
        acc[mi][ni] = __builtin_amdgcn_mfma_f32_16x16x32_bf16(af[mi], bfr[ni], acc[mi][ni], 0, 0, 0);
  }

#pragma unroll
  for (int mi = 0; mi < 2; mi++)
#pragma unroll
    for (int ni = 0; ni < 4; ni++)
#pragma unroll
      for (int r2 = 0; r2 < 4; r2++) {
        int row = row0 + wm * 32 + mi * 16 + cq * 4 + r2;
        int col = col0 + wn * 64 + ni * 16 + cl;
        float v = acc[mi][ni][r2];
        if (EPI == 1) {
          v += bias[col];
          v = 0.5f * v * (1.f + erff(v * 0.70710678118654752f));
          Cout[(size_t)row * NN + col] = __float2bfloat16(v);
        } else {
          Cout[(size_t)sk * MM * NN + (size_t)row * NN + col] = __float2bfloat16(v);
        }
      }
}

// ---------------- ChannelNorm (+conv bias, sum NS bf16 split-K partials) + ReLU -> bf16
template <int NS>
__global__ __launch_bounds__(512) void k_cnorm(const __hip_bfloat16* __restrict__ g,
                                               const float* __restrict__ cb,
                                               const float* __restrict__ gw, const float* __restrict__ gb,
                                               __hip_bfloat16* __restrict__ out, size_t stride) {
  int wave = threadIdx.x >> 6, lane = threadIdx.x & 63;
  size_t row = (size_t)blockIdx.x * 8 + wave;
  float v[8];
  {
    float4 c0 = *(const float4*)(cb + lane * 8), c1 = *(const float4*)(cb + lane * 8 + 4);
    v[0] = c0.x; v[1] = c0.y; v[2] = c0.z; v[3] = c0.w;
    v[4] = c1.x; v[5] = c1.y; v[6] = c1.z; v[7] = c1.w;
  }
#pragma unroll
  for (int s = 0; s < NS; s++) add_bf8(g + s * stride + row * NC + lane * 8, v);
  float s = 0.f, q = 0.f;
#pragma unroll
  for (int j = 0; j < 8; j++) { s += v[j]; q += v[j] * v[j]; }
#pragma unroll
  for (int off = 32; off > 0; off >>= 1) {
    s += __shfl_xor(s, off, 64);
    q += __shfl_xor(q, off, 64);
  }
  float mean = s * (1.f / NC);
  float var = fmaxf((q - s * s * (1.f / NC)) * (1.f / (NC - 1)), 0.f);
  float rstd = rsqrtf(var + EPSF);
  float4 w0 = *(const float4*)(gw + lane * 8), w1 = *(const float4*)(gw + lane * 8 + 4);
  float4 b0 = *(const float4*)(gb + lane * 8), b1 = *(const float4*)(gb + lane * 8 + 4);
  float gwv[8] = {w0.x, w0.y, w0.z, w0.w, w1.x, w1.y, w1.z, w1.w};
  float gbv[8] = {b0.x, b0.y, b0.z, b0.w, b1.x, b1.y, b1.z, b1.w};
  union { __hip_bfloat16 h[8]; uint4 u; } pk;
#pragma unroll
  for (int j = 0; j < 8; j++)
    pk.h[j] = __float2bfloat16(fmaxf((v[j] - mean) * rstd * gwv[j] + gbv[j], 0.f));
  *(uint4*)(out + row * NC + lane * 8) = pk.u;
}

// ---------------- fused head: sum NS bf16 partials + bias + GELU, dot w3, sigmoid ----
template <int NS>
__global__ __launch_bounds__(256) void k_head(const __hip_bfloat16* __restrict__ g,
                                              const float* __restrict__ b2,
                                              const float* __restrict__ w3, const float* __restrict__ b3,
                                              float* __restrict__ imp) {
  __shared__ float red[4];
  int row = blockIdx.x, tid = threadIdx.x;
  int c = tid * 8;
  float v[8];
  {
    float4 x0 = *(const float4*)(b2 + c), x1 = *(const float4*)(b2 + c + 4);
    v[0] = x0.x; v[1] = x0.y; v[2] = x0.z; v[3] = x0.w;
    v[4] = x1.x; v[5] = x1.y; v[6] = x1.z; v[7] = x1.w;
  }
#pragma unroll
  for (int s = 0; s < NS; s++) add_bf8(g + (size_t)s * (2048 * DM) + (size_t)row * DM + c, v);
  float a = 0.f;
  float4 w0 = *(const float4*)(w3 + c), w1 = *(const float4*)(w3 + c + 4);
  float wv[8] = {w0.x, w0.y, w0.z, w0.w, w1.x, w1.y, w1.z, w1.w};
#pragma unroll
  for (int j = 0; j < 8; j++) {
    float z = 0.5f * v[j] * (1.f + erff(v[j] * 0.70710678118654752f));
    a += z * wv[j];
  }
#pragma unroll
  for (int off = 32; off > 0; off >>= 1) a += __shfl_down(a, off, 64);
  int lane = tid & 63, wid = tid >> 6;
  if (lane == 0) red[wid] = a;
  __syncthreads();
  if (tid == 0) {
    float s = red[0] + red[1] + red[2] + red[3] + b3[0];
    imp[row] = 1.f / (1.f + expf(-s)) + TEMPF;
  }
}

__device__ __forceinline__ float dfun(float cv, int n) {
  float d = fmaxf(cv - (float)n, 0.f);
  if (n < TN - 1) d = fminf(d, 1.f);
  return d;
}

// ---------------- fused cumsum + pool + final ChannelNorm + ReLU, write [B][C][TN] ----
__global__ __launch_bounds__(512) void k_poolfinal(const __hip_bfloat16* __restrict__ f,
                                                   const float* __restrict__ imp,
                                                   const float* __restrict__ gw, const float* __restrict__ gb,
                                                   float* __restrict__ out) {
  __shared__ float wt[T3];
  __shared__ float wsum[8];
  __shared__ float red[16];
  int b = blockIdx.x / TN, n = blockIdx.x % TN;
  int tid = threadIdx.x, wave = tid >> 6, lane = tid & 63;
  float own = imp[b * T3 + tid];
  float s = own;
#pragma unroll
  for (int off = 1; off < 64; off <<= 1) {
    float t = __shfl_up(s, off, 64);
    if (lane >= off) s += t;
  }
  if (lane == 63) wsum[wave] = s;
  __syncthreads();
  float prefix = 0.f, total = 0.f;
#pragma unroll
  for (int w = 0; w < 8; w++) {
    float ws_ = wsum[w];
    total += ws_;
    if (w < wave) prefix += ws_;
  }
  float scale = (float)TN / total;
  float incl = (prefix + s) * scale;
  float excl = (prefix + s - own) * scale;
  wt[tid] = dfun(incl, n) - dfun(excl, n);
  __syncthreads();
  float acc = 0.f;
  for (int t = 0; t < T3; t++) {
    float w = wt[t];
    if (w != 0.f) acc += w * __bfloat162float(f[((size_t)b * T3 + t) * NC + tid]);
  }
  float sv = acc, q = acc * acc;
  blk_sum2_512(sv, q, red);
  float mean = sv * (1.f / NC);
  float var = fmaxf((q - sv * sv * (1.f / NC)) * (1.f / (NC - 1)), 0.f);
  float y = (acc - mean) * rsqrtf(var + EPSF) * gw[tid] + gb[tid];
  out[((size_t)b * NC + tid) * TN + n] = fmaxf(y, 0.f);
}

extern "C" void kernel_launch(void* const* d_in, const int* in_sizes, int n_in,
                              void* d_out, int out_size, void* d_ws, size_t ws_size,
                              hipStream_t stream) {
  const float* x   = (const float*)d_in[0];
  const float* c0w = (const float*)d_in[1];  const float* c0b = (const float*)d_in[2];
  const float* c1w = (const float*)d_in[3];  const float* c1b = (const float*)d_in[4];
  const float* c2w = (const float*)d_in[5];  const float* c2b = (const float*)d_in[6];
  const float* c3w = (const float*)d_in[7];  const float* c3b = (const float*)d_in[8];
  const float* mw1 = (const float*)d_in[9];  const float* mb1 = (const float*)d_in[10];
  const float* mw2 = (const float*)d_in[11]; const float* mb2 = (const float*)d_in[12];
  const float* mw3 = (const float*)d_in[13]; const float* mb3 = (const float*)d_in[14];
  const float* n0w = (const float*)d_in[15]; const float* n0b = (const float*)d_in[16];
  const float* n1w = (const float*)d_in[17]; const float* n1b = (const float*)d_in[18];
  const float* n2w = (const float*)d_in[19]; const float* n2b = (const float*)d_in[20];
  const float* n3w = (const float*)d_in[21]; const float* n3b = (const float*)d_in[22];
  const float* n4w = (const float*)d_in[23]; const float* n4b = (const float*)d_in[24];

  char* base = (char*)d_ws;
  // Workspace map (MiB). Peak 82 MiB.
  __hip_bfloat16* h0b  = (__hip_bfloat16*)(base);                     // [0,32): conv0 out; dead after conv1-gemm
  __hip_bfloat16* h1b  = (__hip_bfloat16*)(base);                     // reuse [0,8)
  __hip_bfloat16* h2b  = (__hip_bfloat16*)(base + (8u << 20));        // reuse [8,12)
  __hip_bfloat16* h3b  = (__hip_bfloat16*)(base + (12u << 20));       // reuse [12,14)
  __hip_bfloat16* z1b  = (__hip_bfloat16*)(base + (14u << 20));       // reuse [14,22)
  float*          imp  = (float*)(base + (22u << 20));                // reuse [22,+8K)
  __hip_bfloat16* g    = (__hip_bfloat16*)(base + (32u << 20));       // [32,64): bf16 split-K partials
  __hip_bfloat16* wm1t = (__hip_bfloat16*)(base + (64u << 20));       // [64,66)
  __hip_bfloat16* wt2  = (__hip_bfloat16*)(base + (66u << 20));       // [66,68)
  __hip_bfloat16* wt3  = (__hip_bfloat16*)(base + (68u << 20));       // [68,70)
  __hip_bfloat16* wt1  = (__hip_bfloat16*)(base + (70u << 20));       // [70,74)
  __hip_bfloat16* wm2t = (__hip_bfloat16*)(base + (74u << 20));       // [74,82)
  float* outp = (float*)d_out;

  k_prep<<<6656, 256, 0, stream>>>(c1w, c2w, c3w, mw1, mw2, wt1, wt2, wt3, wm1t, wm2t);
  k_conv0<<<NB * (T0 / 8), 512, 0, stream>>>(x, c0w, c0b, n0w, n0b, h0b);

  // conv1: M=8192, K=4096, N=512, 256x128 tiles, SK4 -> 512 blocks (2/CU @ 256-reg cap)
  k_gemm2<1, 8192, 2048, 4, 2, 4096, 512, 4, 8192><<<512, 256, 0, stream>>>(h0b, wt1, g);
  k_cnorm<4><<<8192 / 8, 512, 0, stream>>>(g, c1b, n1w, n1b, h1b, (size_t)8192 * 512);
  // conv2: M=4096, K=2048, 256x128, SK8 -> 512 blocks
  k_gemm2<1, 2048, 1024, 2, 1, 2048, 512, 8, 4096><<<512, 256, 0, stream>>>(h1b, wt2, g);
  k_cnorm<8><<<4096 / 8, 512, 0, stream>>>(g, c2b, n2w, n2b, h2b, (size_t)4096 * 512);
  // conv3: M=2048, K=2048, 64x128 tiles, SK8 -> 1024 blocks
  k_gemm<1, 1024, 512, 2, 1, 2048, 512, 0, 8, 2048><<<1024, 256, 0, stream>>>(h2b, wt3, nullptr, g);
  k_cnorm<8><<<2048 / 8, 512, 0, stream>>>(g, c3b, n3w, n3b, h3b, (size_t)2048 * 512);

  // mlp1: M=2048, K=512, N=2048, EPI=GELU -> 512 blocks
  k_gemm<0, 0, 1, 0, 0, 512, 2048, 1, 1, 2048><<<512, 256, 0, stream>>>(h3b, wm1t, mb1, z1b);
  // mlp2: M=2048, K=2048, N=2048, 256x128, SK4 -> 512 blocks; head consumes bf16 partials
  k_gemm2<0, 0, 1, 0, 0, 2048, 2048, 4, 2048><<<512, 256, 0, stream>>>(z1b, wm2t, g);

  k_head<4><<<NB * T3, 256, 0, stream>>>(g, mb2, mw3, mb3, imp);
  k_poolfinal<<<NB * TN, 512, 0, stream>>>(h3b, imp, n4w, n4b, outp);
}

// Round 11
// 323.681 us; speedup vs baseline: 1.0057x; 1.0039x over previous
//
#include <hip/hip_runtime.h>
#include <hip/hip_bf16.h>
#include <math.h>

#define NB 4
#define LIN 40960
#define NC 512
#define T0 8192
#define T1 2048
#define T2 1024
#define T3 512
#define TN 256
#define DM 2048
#define EPSF 1e-5f
#define TEMPF 1e-5f

typedef __attribute__((ext_vector_type(8))) short bf16x8;
typedef __attribute__((ext_vector_type(4))) float f32x4;

__device__ __forceinline__ int refl(int t, int T) {
  if (t < 0) t = -t;
  if (t >= T) t = 2 * T - 2 - t;
  return t;
}

__device__ __forceinline__ void gld16(void* lds, const void* g) {
  __builtin_amdgcn_global_load_lds((const __attribute__((address_space(1))) unsigned int*)g,
                                   (__attribute__((address_space(3))) unsigned int*)lds, 16, 0, 0);
}

__device__ __forceinline__ void blk_sum2_512(float& a, float& b, float* scratch) {
#pragma unroll
  for (int off = 32; off > 0; off >>= 1) {
    a += __shfl_down(a, off, 64);
    b += __shfl_down(b, off, 64);
  }
  int lane = threadIdx.x & 63, wid = threadIdx.x >> 6;
  __syncthreads();
  if (lane == 0) { scratch[wid] = a; scratch[8 + wid] = b; }
  __syncthreads();
  float sa = 0.f, sb = 0.f;
#pragma unroll
  for (int i = 0; i < 8; i++) { sa += scratch[i]; sb += scratch[8 + i]; }
  a = sa; b = sb;
}

// load 8 bf16 (16B) -> 8 floats, accumulate
__device__ __forceinline__ void add_bf8(const __hip_bfloat16* p, float* v) {
  union { uint4 u; __hip_bfloat16 h[8]; } pk;
  pk.u = *(const uint4*)p;
#pragma unroll
  for (int j = 0; j < 8; j++) v[j] += __bfloat162float(pk.h[j]);
}

// ---------------- weight prep (single kernel) ----------------
template <int KT>
__device__ __forceinline__ void prep_conv_body(const float* __restrict__ w, __hip_bfloat16* __restrict__ wt,
                                               int co, float* l) {
  const float* wb = w + (size_t)co * 512 * KT;
  for (int i = threadIdx.x; i < 512 * KT; i += 256) l[i] = wb[i];
  __syncthreads();
  __hip_bfloat16* wo = wt + (size_t)co * 512 * KT;
  for (int i = threadIdx.x; i < 512 * KT; i += 256) {
    int kk = i >> 9, ci = i & 511;
    wo[i] = __float2bfloat16(l[ci * KT + kk]);
  }
}

template <int KD, int ND>
__device__ __forceinline__ void prep_mlp_body(const float* __restrict__ w, __hip_bfloat16* __restrict__ wt,
                                              int bidx, float* sbuf) {
  float(*tile)[33] = (float(*)[33])sbuf;
  int bx = bidx % (ND / 32);
  int by = bidx / (ND / 32);
  int tx = threadIdx.x & 31, ty = threadIdx.x >> 5;
#pragma unroll
  for (int i = 0; i < 32; i += 8)
    tile[ty + i][tx] = w[(size_t)(by * 32 + ty + i) * ND + bx * 32 + tx];
  __syncthreads();
#pragma unroll
  for (int i = 0; i < 32; i += 8)
    wt[(size_t)(bx * 32 + ty + i) * KD + by * 32 + tx] = __float2bfloat16(tile[tx][ty + i]);
}

// 512+512+512+1024+4096 = 6656 blocks
__global__ __launch_bounds__(256) void k_prep(const float* c1w, const float* c2w, const float* c3w,
                                              const float* mw1, const float* mw2,
                                              __hip_bfloat16* wt1, __hip_bfloat16* wt2,
                                              __hip_bfloat16* wt3, __hip_bfloat16* wm1t,
                                              __hip_bfloat16* wm2t) {
  __shared__ float sb[4096];
  int b = blockIdx.x;
  if (b < 512) prep_conv_body<8>(c1w, wt1, b, sb);
  else if (b < 1024) prep_conv_body<4>(c2w, wt2, b - 512, sb);
  else if (b < 1536) prep_conv_body<4>(c3w, wt3, b - 1024, sb);
  else if (b < 2560) prep_mlp_body<512, 2048>(mw1, wm1t, b - 1536, sb);
  else prep_mlp_body<2048, 2048>(mw2, wm2t, b - 2560, sb);
}

// ---------------- conv0 + ChannelNorm + ReLU -> bf16 ----------------
__global__ __launch_bounds__(512) void k_conv0(const float* __restrict__ x, const float* __restrict__ w,
                                               const float* __restrict__ bias, const float* __restrict__ gw,
                                               const float* __restrict__ gb, __hip_bfloat16* __restrict__ out) {
  __shared__ float xv[48];
  __shared__ float tb[512 * 9];
  __shared__ float stats[16];
  int b = blockIdx.x / (T0 / 8);
  int t0 = (blockIdx.x % (T0 / 8)) * 8;
  int tid = threadIdx.x;
  if (tid < 45) xv[tid] = x[(size_t)b * LIN + refl(t0 * 5 - 3 + tid, LIN)];
  __syncthreads();
  float wk[10];
#pragma unroll
  for (int k = 0; k < 10; k++) wk[k] = w[tid * 10 + k];
  float bs = bias[tid];
  float acc[8];
#pragma unroll
  for (int tt = 0; tt < 8; tt++) {
    float a = bs;
#pragma unroll
    for (int k = 0; k < 10; k++) a += xv[tt * 5 + k] * wk[k];
    acc[tt] = a;
    tb[tid * 9 + tt] = a;
  }
  __syncthreads();
  int wave = tid >> 6, lane = tid & 63;
  float s = 0.f, q = 0.f;
#pragma unroll
  for (int j = 0; j < 8; j++) {
    float v = tb[(lane * 8 + j) * 9 + wave];
    s += v; q += v * v;
  }
#pragma unroll
  for (int off = 32; off > 0; off >>= 1) {
    s += __shfl_xor(s, off, 64);
    q += __shfl_xor(q, off, 64);
  }
  if (lane == 0) {
    float mean = s * (1.f / NC);
    float var = fmaxf((q - s * s * (1.f / NC)) * (1.f / (NC - 1)), 0.f);
    stats[wave] = mean;
    stats[8 + wave] = rsqrtf(var + EPSF);
  }
  __syncthreads();
  float gwv = gw[tid], gbv = gb[tid];
#pragma unroll
  for (int tt = 0; tt < 8; tt++) {
    float y = (acc[tt] - stats[tt]) * stats[8 + tt] * gwv + gbv;
    out[((size_t)(b * T0 + t0 + tt)) * NC + tid] = __float2bfloat16(fmaxf(y, 0.f));
  }
}

// ---------------- MFMA GEMM v2: 256x128 block tile, wave=128x64, BK=32, dbuf, SK ----
// Staging addresses strength-reduced: pointers advance +64B/K-step; full recompute only
// at kb0 and 16-step tap boundaries (VALUBusy was ~24% = co-bottleneck with MFMA).
template <int MODE, int TIN_, int TOUT_, int SS, int PP, int KK, int NN, int SPLITK, int MM>
__global__ __launch_bounds__(256, 2) void k_gemm2(const __hip_bfloat16* __restrict__ A,
                                                  const __hip_bfloat16* __restrict__ Bt,
                                                  __hip_bfloat16* __restrict__ Cp) {
  __shared__ __align__(16) __hip_bfloat16 sA[2][256 * 32];
  __shared__ __align__(16) __hip_bfloat16 sB[2][128 * 32];
  const int tid = threadIdx.x;
  const int lane = tid & 63;
  const int wave = tid >> 6;
  const int wm = wave >> 1, wn = wave & 1;
  constexpr int nt = NN / 128;
  constexpr int PS = (MM / 2048) * nt;
  constexpr int KBT = KK / 32;
  const int blk = blockIdx.x;
  const int xs = blk & 7, sl = blk >> 3;
  const int sk = sl / PS, rem = sl % PS;
  const int row0 = ((rem / nt) * 8 + xs) * 256;
  const int col0 = (rem % nt) * 128;
  const int kb0 = (sk * KBT) / SPLITK, kb1 = ((sk + 1) * KBT) / SPLITK;
  const int cq = lane >> 4, cl = lane & 15;

  const char* aP[4];
  const char* bP[2];

  auto stage = [&](int kb, int buf) {
    bool recalc = (kb == kb0) || (MODE == 1 && (kb & 15) == 0);
    if (recalc) {
#pragma unroll
      for (int rr = 0; rr < 4; rr++) {
        int c = rr * 256 + tid;
        int m = c >> 2, kc = c & 3;
        int kcs = kc ^ (m & 3);
        size_t ga;
        if (MODE == 0) {
          ga = (size_t)(row0 + m) * KK + kb * 32 + kcs * 8;
        } else {
          int r = row0 + m;
          int bb = r / TOUT_;
          int t = r - bb * TOUT_;
          int k = (kb * 32) >> 9;
          int ci = ((kb * 32) & 511) + kcs * 8;
          int gt = refl(t * SS - PP + k, TIN_);
          ga = (((size_t)(bb * TIN_ + gt)) << 9) + ci;
        }
        aP[rr] = (const char*)(A + ga);
      }
#pragma unroll
      for (int rr = 0; rr < 2; rr++) {
        int c = rr * 256 + tid;
        int n = c >> 2, kc = c & 3;
        int kcs = kc ^ (n & 3);
        bP[rr] = (const char*)(Bt + (size_t)(col0 + n) * KK + kb * 32 + kcs * 8);
      }
    }
#pragma unroll
    for (int rr = 0; rr < 4; rr++) {
      int c = rr * 256 + tid;
      gld16((char*)&sA[buf][0] + c * 16, aP[rr]);
      aP[rr] += 64;
    }
#pragma unroll
    for (int rr = 0; rr < 2; rr++) {
      int c = rr * 256 + tid;
      gld16((char*)&sB[buf][0] + c * 16, bP[rr]);
      bP[rr] += 64;
    }
  };

  f32x4 acc[8][4];
  const f32x4 zz = {0.f, 0.f, 0.f, 0.f};
#pragma unroll
  for (int mi = 0; mi < 8; mi++)
#pragma unroll
    for (int ni = 0; ni < 4; ni++) acc[mi][ni] = zz;

  stage(kb0, 0);
  const int p = cq ^ (cl & 3);
  for (int kb = kb0; kb < kb1; kb++) {
    int cur = (kb - kb0) & 1;
    __syncthreads();
    if (kb + 1 < kb1) stage(kb + 1, cur ^ 1);
    const short* bA = (const short*)&sA[cur][0];
    const short* bB = (const short*)&sB[cur][0];
    bf16x8 af[8], bfr[4];
#pragma unroll
    for (int mi = 0; mi < 8; mi++)
      af[mi] = *(const bf16x8*)(bA + (wm * 128 + mi * 16 + cl) * 32 + p * 8);
#pragma unroll
    for (int ni = 0; ni < 4; ni++)
      bfr[ni] = *(const bf16x8*)(bB + (wn * 64 + ni * 16 + cl) * 32 + p * 8);
#pragma unroll
    for (int mi = 0; mi < 8; mi++)
#pragma unroll
      for (int ni = 0; ni < 4; ni++)
        acc[mi][ni] = __builtin_amdgcn_mfma_f32_16x16x32_bf16(af[mi], bfr[ni], acc[mi][ni], 0, 0, 0);
  }

  // C/D: col=lane&15, row=(lane>>4)*4+reg; bf16 partial out
#pragma unroll
  for (int mi = 0; mi < 8; mi++)
#pragma unroll
    for (int ni = 0; ni < 4; ni++)
#pragma unroll
      for (int r2 = 0; r2 < 4; r2++) {
        int row = row0 + wm * 128 + mi * 16 + cq * 4 + r2;
        int col = col0 + wn * 64 + ni * 16 + cl;
        Cp[(size_t)sk * MM * NN + (size_t)row * NN + col] = __float2bfloat16(acc[mi][ni][r2]);
      }
}

// ---------------- MFMA GEMM v1: 64x128 tile (conv3, mlp1), same strength reduction ----
template <int MODE, int TIN_, int TOUT_, int SS, int PP, int KK, int NN, int EPI, int SPLITK, int MM>
__global__ __launch_bounds__(256, 4) void k_gemm(const __hip_bfloat16* __restrict__ A,
                                                 const __hip_bfloat16* __restrict__ Bt,
                                                 const float* __restrict__ bias,
                                                 __hip_bfloat16* __restrict__ Cout) {
  __shared__ __align__(16) __hip_bfloat16 sA[2][64 * 32];
  __shared__ __align__(16) __hip_bfloat16 sB[2][128 * 32];
  const int tid = threadIdx.x;
  const int lane = tid & 63;
  const int wave = tid >> 6;
  const int wm = wave >> 1, wn = wave & 1;
  constexpr int nt = NN / 128;
  constexpr int PS = (MM / 512) * nt;
  constexpr int KBT = KK / 32;
  const int blk = blockIdx.x;
  const int xs = blk & 7, sl = blk >> 3;
  const int sk = sl / PS, rem = sl % PS;
  const int row0 = ((rem / nt) * 8 + xs) * 64;
  const int col0 = (rem % nt) * 128;
  const int kb0 = (sk * KBT) / SPLITK, kb1 = ((sk + 1) * KBT) / SPLITK;
  const int cq = lane >> 4, cl = lane & 15;

  const char* aP;
  const char* bP[2];

  auto stage = [&](int kb, int buf) {
    bool recalc = (kb == kb0) || (MODE == 1 && (kb & 15) == 0);
    if (recalc) {
      {
        int m = tid >> 2, kc = tid & 3;
        int kcs = kc ^ (m & 3);
        size_t ga;
        if (MODE == 0) {
          ga = (size_t)(row0 + m) * KK + kb * 32 + kcs * 8;
        } else {
          int r = row0 + m;
          int bb = r / TOUT_;
          int t = r - bb * TOUT_;
          int k = (kb * 32) >> 9;
          int ci = ((kb * 32) & 511) + kcs * 8;
          int gt = refl(t * SS - PP + k, TIN_);
          ga = (((size_t)(bb * TIN_ + gt)) << 9) + ci;
        }
        aP = (const char*)(A + ga);
      }
#pragma unroll
      for (int rr = 0; rr < 2; rr++) {
        int c = rr * 256 + tid;
        int n = c >> 2, kc = c & 3;
        int kcs = kc ^ (n & 3);
        bP[rr] = (const char*)(Bt + (size_t)(col0 + n) * KK + kb * 32 + kcs * 8);
      }
    }
    gld16((char*)&sA[buf][0] + tid * 16, aP);
    aP += 64;
#pragma unroll
    for (int rr = 0; rr < 2; rr++) {
      int c = rr * 256 + tid;
      gld16((char*)&sB[buf][0] + c * 16, bP[rr]);
      bP[rr] += 64;
    }
  };

  f32x4 acc[2][4];
  const f32x4 zz = {0.f, 0.f, 0.f, 0.f};
#pragma unroll
  for (int mi = 0; mi < 2; mi++)
#pragma unroll
    for (int ni = 0; ni < 4; ni++) acc[mi][ni] = zz;

  stage(kb0, 0);
  const int p = cq ^ (cl & 3);
  for (int kb = kb0; kb < kb1; kb++) {
    int cur = (kb - kb0) & 1;
    __syncthreads();
    if (kb + 1 < kb1) stage(kb + 1, cur ^ 1);
    const short* bA = (const short*)&sA[cur][0];
    const short* bB = (const short*)&sB[cur][0];
    bf16x8 af[2], bfr[4];
#pragma unroll
    for (int mi = 0; mi < 2; mi++)
      af[mi] = *(const bf16x8*)(bA + (wm * 32 + mi * 16 + cl) * 32 + p * 8);
#pragma unroll
    for (int ni = 0; ni < 4; ni++)
      bfr[ni] = *(const bf16x8*)(bB + (wn * 64 + ni * 16 + cl) * 32 + p * 8);
#pragma unroll
    for (int mi = 0; mi < 2; mi++)
#pragma unroll
      for (int ni = 0; ni < 4; ni++)
        acc[mi][ni] = __builtin_amdgcn_mfma_f32_16x16x32_bf16(af[mi], bfr[ni], acc[mi][ni], 0, 0, 0);
  }

#pragma unroll
  for (int mi = 0; mi < 2; mi++)
#pragma unroll
    for (int ni = 0; ni < 4; ni++)
#pragma unroll
      for (int r2 = 0; r2 < 4; r2++) {
        int row = row0 + wm * 32 + mi * 16 + cq * 4 + r2;
        int col = col0 + wn * 64 + ni * 16 + cl;
        float v = acc[mi][ni][r2];
        if (EPI == 1) {
          v += bias[col];
          v = 0.5f * v * (1.f + erff(v * 0.70710678118654752f));
          Cout[(size_t)row * NN + col] = __float2bfloat16(v);
        } else {
          Cout[(size_t)sk * MM * NN + (size_t)row * NN + col] = __float2bfloat16(v);
        }
      }
}

// ---------------- ChannelNorm (+conv bias, sum NS bf16 split-K partials) + ReLU -> bf16
template <int NS>
__global__ __launch_bounds__(512) void k_cnorm(const __hip_bfloat16* __restrict__ g,
                                               const float* __restrict__ cb,
                                               const float* __restrict__ gw, const float* __restrict__ gb,
                                               __hip_bfloat16* __restrict__ out, size_t stride) {
  int wave = threadIdx.x >> 6, lane = threadIdx.x & 63;
  size_t row = (size_t)blockIdx.x * 8 + wave;
  float v[8];
  {
    float4 c0 = *(const float4*)(cb + lane * 8), c1 = *(const float4*)(cb + lane * 8 + 4);
    v[0] = c0.x; v[1] = c0.y; v[2] = c0.z; v[3] = c0.w;
    v[4] = c1.x; v[5] = c1.y; v[6] = c1.z; v[7] = c1.w;
  }
#pragma unroll
  for (int s = 0; s < NS; s++) add_bf8(g + s * stride + row * NC + lane * 8, v);
  float s = 0.f, q = 0.f;
#pragma unroll
  for (int j = 0; j < 8; j++) { s += v[j]; q += v[j] * v[j]; }
#pragma unroll
  for (int off = 32; off > 0; off >>= 1) {
    s += __shfl_xor(s, off, 64);
    q += __shfl_xor(q, off, 64);
  }
  float mean = s * (1.f / NC);
  float var = fmaxf((q - s * s * (1.f / NC)) * (1.f / (NC - 1)), 0.f);
  float rstd = rsqrtf(var + EPSF);
  float4 w0 = *(const float4*)(gw + lane * 8), w1 = *(const float4*)(gw + lane * 8 + 4);
  float4 b0 = *(const float4*)(gb + lane * 8), b1 = *(const float4*)(gb + lane * 8 + 4);
  float gwv[8] = {w0.x, w0.y, w0.z, w0.w, w1.x, w1.y, w1.z, w1.w};
  float gbv[8] = {b0.x, b0.y, b0.z, b0.w, b1.x, b1.y, b1.z, b1.w};
  union { __hip_bfloat16 h[8]; uint4 u; } pk;
#pragma unroll
  for (int j = 0; j < 8; j++)
    pk.h[j] = __float2bfloat16(fmaxf((v[j] - mean) * rstd * gwv[j] + gbv[j], 0.f));
  *(uint4*)(out + row * NC + lane * 8) = pk.u;
}

// ---------------- fused head: sum NS bf16 partials + bias + GELU, dot w3, sigmoid ----
template <int NS>
__global__ __launch_bounds__(256) void k_head(const __hip_bfloat16* __restrict__ g,
                                              const float* __restrict__ b2,
                                              const float* __restrict__ w3, const float* __restrict__ b3,
                                              float* __restrict__ imp) {
  __shared__ float red[4];
  int row = blockIdx.x, tid = threadIdx.x;
  int c = tid * 8;
  float v[8];
  {
    float4 x0 = *(const float4*)(b2 + c), x1 = *(const float4*)(b2 + c + 4);
    v[0] = x0.x; v[1] = x0.y; v[2] = x0.z; v[3] = x0.w;
    v[4] = x1.x; v[5] = x1.y; v[6] = x1.z; v[7] = x1.w;
  }
#pragma unroll
  for (int s = 0; s < NS; s++) add_bf8(g + (size_t)s * (2048 * DM) + (size_t)row * DM + c, v);
  float a = 0.f;
  float4 w0 = *(const float4*)(w3 + c), w1 = *(const float4*)(w3 + c + 4);
  float wv[8] = {w0.x, w0.y, w0.z, w0.w, w1.x, w1.y, w1.z, w1.w};
#pragma unroll
  for (int j = 0; j < 8; j++) {
    float z = 0.5f * v[j] * (1.f + erff(v[j] * 0.70710678118654752f));
    a += z * wv[j];
  }
#pragma unroll
  for (int off = 32; off > 0; off >>= 1) a += __shfl_down(a, off, 64);
  int lane = tid & 63, wid = tid >> 6;
  if (lane == 0) red[wid] = a;
  __syncthreads();
  if (tid == 0) {
    float s = red[0] + red[1] + red[2] + red[3] + b3[0];
    imp[row] = 1.f / (1.f + expf(-s)) + TEMPF;
  }
}

__device__ __forceinline__ float dfun(float cv, int n) {
  float d = fmaxf(cv - (float)n, 0.f);
  if (n < TN - 1) d = fminf(d, 1.f);
  return d;
}

// ---------------- fused cumsum + pool + final ChannelNorm + ReLU, write [B][C][TN] ----
__global__ __launch_bounds__(512) void k_poolfinal(const __hip_bfloat16* __restrict__ f,
                                                   const float* __restrict__ imp,
                                                   const float* __restrict__ gw, const float* __restrict__ gb,
                                                   float* __restrict__ out) {
  __shared__ float wt[T3];
  __shared__ float wsum[8];
  __shared__ float red[16];
  int b = blockIdx.x / TN, n = blockIdx.x % TN;
  int tid = threadIdx.x, wave = tid >> 6, lane = tid & 63;
  float own = imp[b * T3 + tid];
  float s = own;
#pragma unroll
  for (int off = 1; off < 64; off <<= 1) {
    float t = __shfl_up(s, off, 64);
    if (lane >= off) s += t;
  }
  if (lane == 63) wsum[wave] = s;
  __syncthreads();
  float prefix = 0.f, total = 0.f;
#pragma unroll
  for (int w = 0; w < 8; w++) {
    float ws_ = wsum[w];
    total += ws_;
    if (w < wave) prefix += ws_;
  }
  float scale = (float)TN / total;
  float incl = (prefix + s) * scale;
  float excl = (prefix + s - own) * scale;
  wt[tid] = dfun(incl, n) - dfun(excl, n);
  __syncthreads();
  float acc = 0.f;
  for (int t = 0; t < T3; t++) {
    float w = wt[t];
    if (w != 0.f) acc += w * __bfloat162float(f[((size_t)b * T3 + t) * NC + tid]);
  }
  float sv = acc, q = acc * acc;
  blk_sum2_512(sv, q, red);
  float mean = sv * (1.f / NC);
  float var = fmaxf((q - sv * sv * (1.f / NC)) * (1.f / (NC - 1)), 0.f);
  float y = (acc - mean) * rsqrtf(var + EPSF) * gw[tid] + gb[tid];
  out[((size_t)b * NC + tid) * TN + n] = fmaxf(y, 0.f);
}

extern "C" void kernel_launch(void* const* d_in, const int* in_sizes, int n_in,
                              void* d_out, int out_size, void* d_ws, size_t ws_size,
                              hipStream_t stream) {
  const float* x   = (const float*)d_in[0];
  const float* c0w = (const float*)d_in[1];  const float* c0b = (const float*)d_in[2];
  const float* c1w = (const float*)d_in[3];  const float* c1b = (const float*)d_in[4];
  const float* c2w = (const float*)d_in[5];  const float* c2b = (const float*)d_in[6];
  const float* c3w = (const float*)d_in[7];  const float* c3b = (const float*)d_in[8];
  const float* mw1 = (const float*)d_in[9];  const float* mb1 = (const float*)d_in[10];
  const float* mw2 = (const float*)d_in[11]; const float* mb2 = (const float*)d_in[12];
  const float* mw3 = (const float*)d_in[13]; const float* mb3 = (const float*)d_in[14];
  const float* n0w = (const float*)d_in[15]; const float* n0b = (const float*)d_in[16];
  const float* n1w = (const float*)d_in[17]; const float* n1b = (const float*)d_in[18];
  const float* n2w = (const float*)d_in[19]; const float* n2b = (const float*)d_in[20];
  const float* n3w = (const float*)d_in[21]; const float* n3b = (const float*)d_in[22];
  const float* n4w = (const float*)d_in[23]; const float* n4b = (const float*)d_in[24];

  char* base = (char*)d_ws;
  // Workspace map (MiB). Peak 82 MiB.
  __hip_bfloat16* h0b  = (__hip_bfloat16*)(base);                     // [0,32): conv0 out; dead after conv1-gemm
  __hip_bfloat16* h1b  = (__hip_bfloat16*)(base);                     // reuse [0,8)
  __hip_bfloat16* h2b  = (__hip_bfloat16*)(base + (8u << 20));        // reuse [8,12)
  __hip_bfloat16* h3b  = (__hip_bfloat16*)(base + (12u << 20));       // reuse [12,14)
  __hip_bfloat16* z1b  = (__hip_bfloat16*)(base + (14u << 20));       // reuse [14,22)
  float*          imp  = (float*)(base + (22u << 20));                // reuse [22,+8K)
  __hip_bfloat16* g    = (__hip_bfloat16*)(base + (32u << 20));       // [32,64): bf16 split-K partials
  __hip_bfloat16* wm1t = (__hip_bfloat16*)(base + (64u << 20));       // [64,66)
  __hip_bfloat16* wt2  = (__hip_bfloat16*)(base + (66u << 20));       // [66,68)
  __hip_bfloat16* wt3  = (__hip_bfloat16*)(base + (68u << 20));       // [68,70)
  __hip_bfloat16* wt1  = (__hip_bfloat16*)(base + (70u << 20));       // [70,74)
  __hip_bfloat16* wm2t = (__hip_bfloat16*)(base + (74u << 20));       // [74,82)
  float* outp = (float*)d_out;

  k_prep<<<6656, 256, 0, stream>>>(c1w, c2w, c3w, mw1, mw2, wt1, wt2, wt3, wm1t, wm2t);
  k_conv0<<<NB * (T0 / 8), 512, 0, stream>>>(x, c0w, c0b, n0w, n0b, h0b);

  // conv1: M=8192, K=4096, N=512, 256x128 tiles, SK4 -> 512 blocks (2/CU)
  k_gemm2<1, 8192, 2048, 4, 2, 4096, 512, 4, 8192><<<512, 256, 0, stream>>>(h0b, wt1, g);
  k_cnorm<4><<<8192 / 8, 512, 0, stream>>>(g, c1b, n1w, n1b, h1b, (size_t)8192 * 512);
  // conv2: M=4096, K=2048, 256x128, SK8 -> 512 blocks
  k_gemm2<1, 2048, 1024, 2, 1, 2048, 512, 8, 4096><<<512, 256, 0, stream>>>(h1b, wt2, g);
  k_cnorm<8><<<4096 / 8, 512, 0, stream>>>(g, c2b, n2w, n2b, h2b, (size_t)4096 * 512);
  // conv3: M=2048, K=2048, 64x128 tiles, SK8 -> 1024 blocks
  k_gemm<1, 1024, 512, 2, 1, 2048, 512, 0, 8, 2048><<<1024, 256, 0, stream>>>(h2b, wt3, nullptr, g);
  k_cnorm<8><<<2048 / 8, 512, 0, stream>>>(g, c3b, n3w, n3b, h3b, (size_t)2048 * 512);

  // mlp1: M=2048, K=512, N=2048, EPI=GELU -> 512 blocks
  k_gemm<0, 0, 1, 0, 0, 512, 2048, 1, 1, 2048><<<512, 256, 0, stream>>>(h3b, wm1t, mb1, z1b);
  // mlp2: M=2048, K=2048, N=2048, 256x128, SK4 -> 512 blocks; head consumes bf16 partials
  k_gemm2<0, 0, 1, 0, 0, 2048, 2048, 4, 2048><<<512, 256, 0, stream>>>(z1b, wm2t, g);

  k_head<4><<<NB * T3, 256, 0, stream>>>(g, mb2, mw3, mb3, imp);
  k_poolfinal<<<NB * TN, 512, 0, stream>>>(h3b, imp, n4w, n4b, outp);
}